// Round 3
// baseline (488.531 us; speedup 1.0000x reference)
//
#include <hip/hip_runtime.h>
#include <math.h>

#define B_ 16
#define L_ 512
#define D_ 768
#define H_ 12
#define K_ 128
#define U_ 256
#define NH_ 4
#define HD_ 64
#define OUTROWS_ 130   // 1 class + 128 preserved + 1 new
#define IMP_G_ 96      // importance partial groups: 48 chunks x 2 row-halves

// ---------------------------------------------------------------------------
// Block reduction helpers. 768-thread (12 wave) and 512-thread (8 wave).
// ---------------------------------------------------------------------------
__device__ __forceinline__ float blk_max768(float v, float* red, int t) {
  __syncthreads();
  #pragma unroll
  for (int o = 32; o > 0; o >>= 1) v = fmaxf(v, __shfl_down(v, o, 64));
  if ((t & 63) == 0) red[t >> 6] = v;
  __syncthreads();
  if (t == 0) {
    float r = red[0];
    #pragma unroll
    for (int w = 1; w < 12; ++w) r = fmaxf(r, red[w]);
    red[0] = r;
  }
  __syncthreads();
  return red[0];
}

__device__ __forceinline__ float blk_sum768(float v, float* red, int t) {
  __syncthreads();
  #pragma unroll
  for (int o = 32; o > 0; o >>= 1) v += __shfl_down(v, o, 64);
  if ((t & 63) == 0) red[t >> 6] = v;
  __syncthreads();
  if (t == 0) {
    float r = 0.f;
    #pragma unroll
    for (int w = 0; w < 12; ++w) r += red[w];
    red[0] = r;
  }
  __syncthreads();
  return red[0];
}

__device__ __forceinline__ float blk_max512(float v, float* red, int t) {
  __syncthreads();
  #pragma unroll
  for (int o = 32; o > 0; o >>= 1) v = fmaxf(v, __shfl_down(v, o, 64));
  if ((t & 63) == 0) red[t >> 6] = v;
  __syncthreads();
  if (t == 0) {
    float r = red[0];
    #pragma unroll
    for (int w = 1; w < 8; ++w) r = fmaxf(r, red[w]);
    red[0] = r;
  }
  __syncthreads();
  return red[0];
}

__device__ __forceinline__ float blk_sum512(float v, float* red, int t) {
  __syncthreads();
  #pragma unroll
  for (int o = 32; o > 0; o >>= 1) v += __shfl_down(v, o, 64);
  if ((t & 63) == 0) red[t >> 6] = v;
  __syncthreads();
  if (t == 0) {
    float r = 0.f;
    #pragma unroll
    for (int w = 0; w < 8; ++w) r += red[w];
    red[0] = r;
  }
  __syncthreads();
  return red[0];
}

// ---------------------------------------------------------------------------
// Importance partials: part[b][chunk*2+rhalf][l] = (1/H) * sum over 64 rows.
// float4 columns: 256 threads = 128 float4-cols x 2 row-halves.
// Grid (48, B). No atomics, no memset.
// ---------------------------------------------------------------------------
__global__ __launch_bounds__(256) void importance_kernel(
    const float* __restrict__ scores, float* __restrict__ part) {
  const int b = blockIdx.y, chunk = blockIdx.x, t = threadIdx.x;
  const int qcol = t & 127;     // float4 column
  const int rhalf = t >> 7;     // 0/1
  const float4* base = (const float4*)scores +
      ((size_t)(b * (H_ * L_) + chunk * 128 + rhalf)) * 128 + qcol;
  float4 a = make_float4(0.f, 0.f, 0.f, 0.f);
  #pragma unroll 8
  for (int r = 0; r < 64; ++r) {
    float4 v = base[(size_t)r * 256];  // rows step 2
    a.x += v.x; a.y += v.y; a.z += v.z; a.w += v.w;
  }
  const float s = 1.0f / 12.0f;
  float4 o = make_float4(a.x * s, a.y * s, a.z * s, a.w * s);
  ((float4*)part)[((size_t)b * IMP_G_ + chunk * 2 + rhalf) * 128 + qcol] = o;
}

// ---------------------------------------------------------------------------
// Top-K=128 (rank counting, ballot scan) + fused gather of class + preserved
// rows into out0, + out1 mask row. One block of 512 per batch.
// ---------------------------------------------------------------------------
__global__ __launch_bounds__(512) void topk_gather_kernel(
    const float* __restrict__ part, const float* __restrict__ mask,
    const float* __restrict__ hidden, float* __restrict__ out0,
    float* __restrict__ out1) {
  __shared__ float v[L_];
  __shared__ int lidx[K_];
  __shared__ int wcnt[8];
  const int b = blockIdx.x, t = threadIdx.x;
  // reduce 96 partials -> importance[t]
  {
    const float* pp = part + (size_t)b * IMP_G_ * L_ + t;
    float s = 0.f;
    #pragma unroll 8
    for (int g = 0; g < IMP_G_; ++g) s += pp[(size_t)g * L_];
    v[t] = s;
  }
  __syncthreads();
  const float mv = v[t];
  int cnt = 0;
  #pragma unroll 8
  for (int j = 0; j < L_; ++j) {
    float o = v[j];
    cnt += (o > mv) || (o == mv && j < t);  // stable tie-break like lax.top_k
  }
  const bool sel = cnt < K_;
  const unsigned long long ball = __ballot(sel);
  const int lane = t & 63, wave = t >> 6;
  if (lane == 0) wcnt[wave] = __popcll(ball);
  __syncthreads();
  int base = 0;
  for (int w = 0; w < wave; ++w) base += wcnt[w];
  const int pos = base + __popcll(ball & ((1ull << lane) - 1ull));
  if (sel) {
    lidx[pos] = t;
    out1[b * OUTROWS_ + 1 + pos] = mask[b * L_ + t];
  }
  if (t == 0) {
    out1[b * OUTROWS_ + 0] = 0.f;
    out1[b * OUTROWS_ + OUTROWS_ - 1] = 0.f;
  }
  __syncthreads();
  // gather rows 0..128 (class + preserved), float4 copies
  const float4* hb4 = (const float4*)(hidden + (size_t)b * L_ * D_);
  float4* ob4 = (float4*)(out0 + (size_t)b * OUTROWS_ * D_);
  const int NG = (K_ + 1) * 192;  // 129 rows * 192 float4
  for (int i = t; i < NG; i += 512) {
    const int r = i / 192;
    const int c = i - r * 192;
    const int src = (r == 0) ? 0 : lidx[r - 1];
    ob4[r * 192 + c] = hb4[src * 192 + c];
  }
}

// ---------------------------------------------------------------------------
// sentences partials: sent_part[b][chunk][d] = sum over 32 l's of att*hidden.
// Grid (B, 16), block 768 (t = d, coalesced). Mask softmax recomputed locally.
// ---------------------------------------------------------------------------
__global__ __launch_bounds__(768) void sent_kernel(
    const float* __restrict__ hidden, const float* __restrict__ mask,
    float* __restrict__ sent_part) {
  __shared__ float att[L_];
  __shared__ float red[16];
  const int b = blockIdx.x, chunk = blockIdx.y, t = threadIdx.x;
  float m = (t < L_) ? mask[b * L_ + t] : -INFINITY;
  float mx = blk_max768(m, red, t);
  float e = (t < L_) ? expf(m - mx) : 0.f;
  float se = blk_sum768(e, red, t);
  if (t < L_) att[t] = e / se;
  __syncthreads();
  const int l0 = chunk * 32;
  const float* hp = hidden + ((size_t)b * L_ + l0) * D_ + t;
  float acc = 0.f;
  #pragma unroll 8
  for (int l = 0; l < 32; ++l) acc += att[l0 + l] * hp[(size_t)l * D_];
  sent_part[((size_t)b * 16 + chunk) * D_ + t] = acc;
}

// ---------------------------------------------------------------------------
// q[u] = sent . Wq[u,:]; wq_eff[h,d] = sum_{j<64} q[64h+j] * Wk[64h+j, d]
// Grid B, block 768. Reduces the 16 sent partials on load.
// ---------------------------------------------------------------------------
__global__ __launch_bounds__(768) void qproj_kernel(
    const float* __restrict__ sent_part, const float* __restrict__ Wq,
    const float* __restrict__ Wk, float* __restrict__ wqe) {
  __shared__ float s[D_];
  __shared__ float qv[U_];
  const int b = blockIdx.x, t = threadIdx.x;
  {
    const float* sp = sent_part + (size_t)b * 16 * D_ + t;
    float a = 0.f;
    #pragma unroll
    for (int c = 0; c < 16; ++c) a += sp[(size_t)c * D_];
    s[t] = a;
  }
  __syncthreads();
  if (t < U_) {
    const float* wr = Wq + (size_t)t * D_;
    float acc = 0.f;
    #pragma unroll 4
    for (int d = 0; d < D_; ++d) acc += s[d] * wr[d];
    qv[t] = acc;
  }
  __syncthreads();
  #pragma unroll
  for (int h = 0; h < NH_; ++h) {
    float acc = 0.f;
    const float* wk = Wk + (size_t)(h * HD_) * D_ + t;
    #pragma unroll 4
    for (int j = 0; j < HD_; ++j) acc += qv[h * HD_ + j] * wk[(size_t)j * D_];
    wqe[((size_t)b * NH_ + h) * D_ + t] = acc;
  }
}

// ---------------------------------------------------------------------------
// scores[b,h,l] = (hidden[b,l,:] . wq_eff[b,h,:]) / sqrt(D), masked.
// Grid (B, 16), block 256; wave handles 8 rows; float4 loads.
// ---------------------------------------------------------------------------
__global__ __launch_bounds__(256) void score_kernel(
    const float* __restrict__ hidden, const float* __restrict__ mask,
    const float* __restrict__ wqe, float* __restrict__ scores) {
  __shared__ float4 wq4[NH_ * 192];
  const int b = blockIdx.x, chunk = blockIdx.y, t = threadIdx.x;
  {
    const float4* wsrc = (const float4*)(wqe + (size_t)b * NH_ * D_);
    for (int i = t; i < NH_ * 192; i += 256) wq4[i] = wsrc[i];
  }
  __syncthreads();
  const int wave = t >> 6, lane = t & 63;
  const float scale = 0.03608439182435161f;  // 1/sqrt(768)
  #pragma unroll
  for (int r = 0; r < 8; ++r) {
    const int l = chunk * 32 + wave * 8 + r;
    const float4* hr4 = (const float4*)(hidden + ((size_t)b * L_ + l) * D_);
    float s0 = 0.f, s1 = 0.f, s2 = 0.f, s3 = 0.f;
    #pragma unroll
    for (int jj = 0; jj < 3; ++jj) {
      const int c = lane + 64 * jj;
      const float4 hv = hr4[c];
      const float4 w0 = wq4[0 * 192 + c];
      const float4 w1 = wq4[1 * 192 + c];
      const float4 w2 = wq4[2 * 192 + c];
      const float4 w3 = wq4[3 * 192 + c];
      s0 += hv.x * w0.x + hv.y * w0.y + hv.z * w0.z + hv.w * w0.w;
      s1 += hv.x * w1.x + hv.y * w1.y + hv.z * w1.z + hv.w * w1.w;
      s2 += hv.x * w2.x + hv.y * w2.y + hv.z * w2.z + hv.w * w2.w;
      s3 += hv.x * w3.x + hv.y * w3.y + hv.z * w3.z + hv.w * w3.w;
    }
    #pragma unroll
    for (int o = 32; o > 0; o >>= 1) {
      s0 += __shfl_down(s0, o, 64);
      s1 += __shfl_down(s1, o, 64);
      s2 += __shfl_down(s2, o, 64);
      s3 += __shfl_down(s3, o, 64);
    }
    if (lane == 0) {
      const bool kp = mask[b * L_ + l] < -10.f;
      float* sp = scores + (size_t)b * NH_ * L_ + l;
      sp[0 * L_] = kp ? -INFINITY : s0 * scale;
      sp[1 * L_] = kp ? -INFINITY : s1 * scale;
      sp[2 * L_] = kp ? -INFINITY : s2 * scale;
      sp[3 * L_] = kp ? -INFINITY : s3 * scale;
    }
  }
}

// ---------------------------------------------------------------------------
// In-place softmax over l per (b,h). Grid (B, NH), block 512.
// ---------------------------------------------------------------------------
__global__ __launch_bounds__(512) void prob_kernel(float* __restrict__ scores) {
  __shared__ float red[8];
  const int b = blockIdx.x, h = blockIdx.y, t = threadIdx.x;
  float* sp = scores + ((size_t)b * NH_ + h) * L_;
  float v = sp[t];
  float mx = blk_max512(v, red, t);
  float e = expf(v - mx);
  float se = blk_sum512(e, red, t);
  sp[t] = e / se;
}

// ---------------------------------------------------------------------------
// ctx partials: ctx_part[b][chunk][h][d] over 32 l's. Grid (B,16), block 768.
// ---------------------------------------------------------------------------
__global__ __launch_bounds__(768) void ctx_kernel(
    const float* __restrict__ hidden, const float* __restrict__ probs,
    float* __restrict__ ctx_part) {
  __shared__ float pr[NH_][32];
  const int b = blockIdx.x, chunk = blockIdx.y, t = threadIdx.x;
  const int l0 = chunk * 32;
  if (t < NH_ * 32)
    pr[t >> 5][t & 31] = probs[((size_t)b * NH_ + (t >> 5)) * L_ + l0 + (t & 31)];
  __syncthreads();
  const float* hp = hidden + ((size_t)b * L_ + l0) * D_ + t;
  float c0 = 0.f, c1 = 0.f, c2 = 0.f, c3 = 0.f;
  #pragma unroll 8
  for (int l = 0; l < 32; ++l) {
    float hv = hp[(size_t)l * D_];
    c0 += pr[0][l] * hv;
    c1 += pr[1][l] * hv;
    c2 += pr[2][l] * hv;
    c3 += pr[3][l] * hv;
  }
  float* cb = ctx_part + ((size_t)b * 16 + chunk) * NH_ * D_ + t;
  cb[0 * D_] = c0;
  cb[1 * D_] = c1;
  cb[2 * D_] = c2;
  cb[3 * D_] = c3;
}

// ---------------------------------------------------------------------------
// out[u] = ctx[h(u),:] . Wv[u,:]; new_token[d] = bo[d] + sum_u out[u]*Wo[d,u]
// Grid B, block 768. Reduces the 16 ctx partials on load; writes out0 row 129.
// ---------------------------------------------------------------------------
__global__ __launch_bounds__(768) void out_kernel(
    const float* __restrict__ ctx_part, const float* __restrict__ Wv,
    const float* __restrict__ Wo, const float* __restrict__ bo,
    float* __restrict__ out0) {
  __shared__ float cs[NH_ * D_];
  __shared__ float outv[U_];
  const int b = blockIdx.x, t = threadIdx.x;
  for (int i = t; i < NH_ * D_; i += 768) {
    const float* cp = ctx_part + (size_t)b * 16 * NH_ * D_ + i;
    float a = 0.f;
    #pragma unroll
    for (int c = 0; c < 16; ++c) a += cp[(size_t)c * NH_ * D_];
    cs[i] = a;
  }
  __syncthreads();
  if (t < U_) {
    const int h = t >> 6;
    const float* wv = Wv + (size_t)t * D_;
    float acc = 0.f;
    #pragma unroll 4
    for (int d = 0; d < D_; ++d) acc += cs[h * D_ + d] * wv[d];
    outv[t] = acc;
  }
  __syncthreads();
  const float* wo = Wo + (size_t)t * U_;
  float acc = bo[t];
  #pragma unroll 4
  for (int u = 0; u < U_; ++u) acc += outv[u] * wo[u];
  out0[((size_t)b * OUTROWS_ + (OUTROWS_ - 1)) * D_ + t] = acc;
}

extern "C" void kernel_launch(void* const* d_in, const int* in_sizes, int n_in,
                              void* d_out, int out_size, void* d_ws, size_t ws_size,
                              hipStream_t stream) {
  const float* hidden = (const float*)d_in[0];
  const float* mask   = (const float*)d_in[1];
  const float* sas    = (const float*)d_in[2];
  const float* Wq     = (const float*)d_in[3];
  const float* Wk     = (const float*)d_in[4];
  const float* Wv     = (const float*)d_in[5];
  const float* Wo     = (const float*)d_in[6];
  const float* bo     = (const float*)d_in[7];

  float* out0 = (float*)d_out;                       // (B,130,D)
  float* out1 = out0 + (size_t)B_ * OUTROWS_ * D_;   // (B,1,1,130)

  // Workspace layout (floats) — all partial buffers fully overwritten, no init.
  float* part      = (float*)d_ws;                       // B*96*L   = 786432
  float* sent_part = part + (size_t)B_ * IMP_G_ * L_;    // B*16*D   = 196608
  float* ctx_part  = sent_part + (size_t)B_ * 16 * D_;   // B*16*4*D = 786432
  float* wqe       = ctx_part + (size_t)B_ * 16 * NH_ * D_;  // B*4*D = 49152
  float* scores    = wqe + (size_t)B_ * NH_ * D_;        // B*4*L    = 32768

  importance_kernel<<<dim3(48, B_), 256, 0, stream>>>(sas, part);
  sent_kernel<<<dim3(B_, 16), 768, 0, stream>>>(hidden, mask, sent_part);
  topk_gather_kernel<<<B_, 512, 0, stream>>>(part, mask, hidden, out0, out1);
  qproj_kernel<<<B_, 768, 0, stream>>>(sent_part, Wq, Wk, wqe);
  score_kernel<<<dim3(B_, 16), 256, 0, stream>>>(hidden, mask, wqe, scores);
  prob_kernel<<<dim3(B_, NH_), 512, 0, stream>>>(scores);
  ctx_kernel<<<dim3(B_, 16), 768, 0, stream>>>(hidden, scores, ctx_part);
  out_kernel<<<B_, 768, 0, stream>>>(ctx_part, Wv, Wo, bo, out0);
}

// Round 4
// 400.246 us; speedup vs baseline: 1.2206x; 1.2206x over previous
//
#include <hip/hip_runtime.h>
#include <math.h>

#define B_ 16
#define L_ 512
#define D_ 768
#define H_ 12
#define K_ 128
#define U_ 256
#define NH_ 4
#define HD_ 64
#define OUTROWS_ 130   // 1 class + 128 preserved + 1 new
#define IMP_G_ 96      // importance partial groups: 48 chunks x 2 row-halves

// ---------------------------------------------------------------------------
// Block reduction helpers (768-thread = 12 waves).
// ---------------------------------------------------------------------------
__device__ __forceinline__ float blk_max768(float v, float* red, int t) {
  __syncthreads();
  #pragma unroll
  for (int o = 32; o > 0; o >>= 1) v = fmaxf(v, __shfl_down(v, o, 64));
  if ((t & 63) == 0) red[t >> 6] = v;
  __syncthreads();
  if (t == 0) {
    float r = red[0];
    #pragma unroll
    for (int w = 1; w < 12; ++w) r = fmaxf(r, red[w]);
    red[0] = r;
  }
  __syncthreads();
  return red[0];
}

__device__ __forceinline__ float blk_sum768(float v, float* red, int t) {
  __syncthreads();
  #pragma unroll
  for (int o = 32; o > 0; o >>= 1) v += __shfl_down(v, o, 64);
  if ((t & 63) == 0) red[t >> 6] = v;
  __syncthreads();
  if (t == 0) {
    float r = 0.f;
    #pragma unroll
    for (int w = 0; w < 12; ++w) r += red[w];
    red[0] = r;
  }
  __syncthreads();
  return red[0];
}

// ---------------------------------------------------------------------------
// Importance partials: part[b][chunk*2+rhalf][l] = (1/H)*sum over 64 rows.
// Grid (48, B), block 256 = 128 float4-cols x 2 row-halves. ~201 MB read.
// ---------------------------------------------------------------------------
__global__ __launch_bounds__(256) void importance_kernel(
    const float* __restrict__ scores, float* __restrict__ part) {
  const int b = blockIdx.y, chunk = blockIdx.x, t = threadIdx.x;
  const int qcol = t & 127;
  const int rhalf = t >> 7;
  const float4* base = (const float4*)scores +
      ((size_t)(b * (H_ * L_) + chunk * 128 + rhalf)) * 128 + qcol;
  float4 a = make_float4(0.f, 0.f, 0.f, 0.f);
  #pragma unroll 8
  for (int r = 0; r < 64; ++r) {
    float4 v = base[(size_t)r * 256];
    a.x += v.x; a.y += v.y; a.z += v.z; a.w += v.w;
  }
  const float s = 1.0f / 12.0f;
  float4 o = make_float4(a.x * s, a.y * s, a.z * s, a.w * s);
  ((float4*)part)[((size_t)b * IMP_G_ + chunk * 2 + rhalf) * 128 + qcol] = o;
}

// ---------------------------------------------------------------------------
// sentences partials: sent_part[b][chunk][d] over 32 l's. Grid (B,16), 768 thr.
// ---------------------------------------------------------------------------
__global__ __launch_bounds__(768) void sent_kernel(
    const float* __restrict__ hidden, const float* __restrict__ mask,
    float* __restrict__ sent_part) {
  __shared__ float att[L_];
  __shared__ float red[16];
  const int b = blockIdx.x, chunk = blockIdx.y, t = threadIdx.x;
  float m = (t < L_) ? mask[b * L_ + t] : -INFINITY;
  float mx = blk_max768(m, red, t);
  float e = (t < L_) ? expf(m - mx) : 0.f;
  float se = blk_sum768(e, red, t);
  if (t < L_) att[t] = e / se;
  __syncthreads();
  const int l0 = chunk * 32;
  const float* hp = hidden + ((size_t)b * L_ + l0) * D_ + t;
  float acc = 0.f;
  #pragma unroll 8
  for (int l = 0; l < 32; ++l) acc += att[l0 + l] * hp[(size_t)l * D_];
  sent_part[((size_t)b * 16 + chunk) * D_ + t] = acc;
}

// ---------------------------------------------------------------------------
// Fused dispatch: blocks 0..63 = qproj per (b,h); blocks 64..79 = topk+gather.
// qproj: reduce sent partials -> q head slice -> wq_eff[b,h,:].
// topk: reduce importance partials -> rank-count topK -> gather rows + mask.
// ---------------------------------------------------------------------------
__global__ __launch_bounds__(768) void qproj_topk_kernel(
    const float* __restrict__ sent_part, const float* __restrict__ Wq,
    const float* __restrict__ Wk, float* __restrict__ wqe,
    const float* __restrict__ part, const float* __restrict__ mask,
    const float* __restrict__ hidden, float* __restrict__ out0,
    float* __restrict__ out1) {
  __shared__ float s[D_];
  __shared__ float qvh[HD_];
  __shared__ float v[L_];
  __shared__ int lidx[K_];
  __shared__ int wcnt[12];
  const int t = threadIdx.x;
  const int wave = t >> 6, lane = t & 63;

  if (blockIdx.x < 64) {
    const int b = blockIdx.x >> 2, h = blockIdx.x & 3;
    // reduce sent partials
    {
      const float* sp = sent_part + (size_t)b * 16 * D_ + t;
      float a = 0.f;
      #pragma unroll
      for (int c = 0; c < 16; ++c) a += sp[(size_t)c * D_];
      s[t] = a;
    }
    __syncthreads();
    // qvh[u] = s . Wq[h*64+u, :]   (wave-per-u, lane over d)
    for (int u = wave; u < HD_; u += 12) {
      const float* wr = Wq + (size_t)(h * HD_ + u) * D_;
      float acc = 0.f;
      #pragma unroll
      for (int k = 0; k < 12; ++k) {
        const int d = lane + (k << 6);
        acc += wr[d] * s[d];
      }
      #pragma unroll
      for (int o = 32; o > 0; o >>= 1) acc += __shfl_down(acc, o, 64);
      if (lane == 0) qvh[u] = acc;
    }
    __syncthreads();
    // wq_eff[b,h,d] = sum_j qvh[j] * Wk[h*64+j, d]   (t = d, coalesced)
    {
      float acc = 0.f;
      const float* wk = Wk + (size_t)(h * HD_) * D_ + t;
      #pragma unroll 4
      for (int j = 0; j < HD_; ++j) acc += qvh[j] * wk[(size_t)j * D_];
      wqe[((size_t)b * NH_ + h) * D_ + t] = acc;
    }
  } else {
    const int b = blockIdx.x - 64;
    if (t < L_) {
      const float* pp = part + (size_t)b * IMP_G_ * L_ + t;
      float sum = 0.f;
      #pragma unroll 8
      for (int g = 0; g < IMP_G_; ++g) sum += pp[(size_t)g * L_];
      v[t] = sum;
    }
    __syncthreads();
    bool sel = false;
    if (t < L_) {
      const float mv = v[t];
      int cnt = 0;
      #pragma unroll 8
      for (int j = 0; j < L_; ++j) {
        float o = v[j];
        cnt += (o > mv) || (o == mv && j < t);  // stable tie-break
      }
      sel = cnt < K_;
    }
    const unsigned long long ball = __ballot(sel);
    if (lane == 0) wcnt[wave] = __popcll(ball);
    __syncthreads();
    int base = 0;
    for (int w = 0; w < wave; ++w) base += wcnt[w];
    const int pos = base + __popcll(ball & ((1ull << lane) - 1ull));
    if (sel) {
      lidx[pos] = t;
      out1[b * OUTROWS_ + 1 + pos] = mask[b * L_ + t];
    }
    if (t == 0) {
      out1[b * OUTROWS_ + 0] = 0.f;
      out1[b * OUTROWS_ + OUTROWS_ - 1] = 0.f;
    }
    __syncthreads();
    // gather rows 0..128 (class + preserved), float4 copies
    const float4* hb4 = (const float4*)(hidden + (size_t)b * L_ * D_);
    float4* ob4 = (float4*)(out0 + (size_t)b * OUTROWS_ * D_);
    const int NG = (K_ + 1) * 192;  // 129 rows * 192 float4
    for (int i = t; i < NG; i += 768) {
      const int r = i / 192;
      const int c = i - r * 192;
      const int src = (r == 0) ? 0 : lidx[r - 1];
      ob4[r * 192 + c] = hb4[src * 192 + c];
    }
  }
}

// ---------------------------------------------------------------------------
// scores[b,h,l] = (hidden[b,l,:] . wq_eff[b,h,:]) / sqrt(D), masked.
// Grid (B, 16), block 256; wave handles 8 rows; float4 loads.
// ---------------------------------------------------------------------------
__global__ __launch_bounds__(256) void score_kernel(
    const float* __restrict__ hidden, const float* __restrict__ mask,
    const float* __restrict__ wqe, float* __restrict__ scores) {
  __shared__ float4 wq4[NH_ * 192];
  const int b = blockIdx.x, chunk = blockIdx.y, t = threadIdx.x;
  {
    const float4* wsrc = (const float4*)(wqe + (size_t)b * NH_ * D_);
    for (int i = t; i < NH_ * 192; i += 256) wq4[i] = wsrc[i];
  }
  __syncthreads();
  const int wave = t >> 6, lane = t & 63;
  const float scale = 0.03608439182435161f;  // 1/sqrt(768)
  #pragma unroll
  for (int r = 0; r < 8; ++r) {
    const int l = chunk * 32 + wave * 8 + r;
    const float4* hr4 = (const float4*)(hidden + ((size_t)b * L_ + l) * D_);
    float s0 = 0.f, s1 = 0.f, s2 = 0.f, s3 = 0.f;
    #pragma unroll
    for (int jj = 0; jj < 3; ++jj) {
      const int c = lane + 64 * jj;
      const float4 hv = hr4[c];
      const float4 w0 = wq4[0 * 192 + c];
      const float4 w1 = wq4[1 * 192 + c];
      const float4 w2 = wq4[2 * 192 + c];
      const float4 w3 = wq4[3 * 192 + c];
      s0 += hv.x * w0.x + hv.y * w0.y + hv.z * w0.z + hv.w * w0.w;
      s1 += hv.x * w1.x + hv.y * w1.y + hv.z * w1.z + hv.w * w1.w;
      s2 += hv.x * w2.x + hv.y * w2.y + hv.z * w2.z + hv.w * w2.w;
      s3 += hv.x * w3.x + hv.y * w3.y + hv.z * w3.z + hv.w * w3.w;
    }
    #pragma unroll
    for (int o = 32; o > 0; o >>= 1) {
      s0 += __shfl_down(s0, o, 64);
      s1 += __shfl_down(s1, o, 64);
      s2 += __shfl_down(s2, o, 64);
      s3 += __shfl_down(s3, o, 64);
    }
    if (lane == 0) {
      const bool kp = mask[b * L_ + l] < -10.f;
      float* sp = scores + (size_t)b * NH_ * L_ + l;
      sp[0 * L_] = kp ? -INFINITY : s0 * scale;
      sp[1 * L_] = kp ? -INFINITY : s1 * scale;
      sp[2 * L_] = kp ? -INFINITY : s2 * scale;
      sp[3 * L_] = kp ? -INFINITY : s3 * scale;
    }
  }
}

// ---------------------------------------------------------------------------
// ctx partials with fused softmax: each block recomputes the 4 row-softmaxes
// (8 KB read + reductions), then accumulates its 32 l's.
// Grid (B,16), block 768 (t = d, coalesced).
// ---------------------------------------------------------------------------
__global__ __launch_bounds__(768) void ctx_prob_kernel(
    const float* __restrict__ hidden, const float* __restrict__ scores,
    float* __restrict__ ctx_part) {
  __shared__ float pr[NH_][32];
  __shared__ float red[16];
  const int b = blockIdx.x, chunk = blockIdx.y, t = threadIdx.x;
  const int l0 = chunk * 32;
  #pragma unroll
  for (int h = 0; h < NH_; ++h) {
    const float* sp = scores + ((size_t)b * NH_ + h) * L_;
    float val = (t < L_) ? sp[t] : -INFINITY;
    float mx = blk_max768(val, red, t);
    float e = (t < L_) ? expf(val - mx) : 0.f;
    float se = blk_sum768(e, red, t);
    if (t >= l0 && t < l0 + 32) pr[h][t - l0] = e / se;
  }
  __syncthreads();
  const float* hp = hidden + ((size_t)b * L_ + l0) * D_ + t;
  float c0 = 0.f, c1 = 0.f, c2 = 0.f, c3 = 0.f;
  #pragma unroll 8
  for (int l = 0; l < 32; ++l) {
    float hv = hp[(size_t)l * D_];
    c0 += pr[0][l] * hv;
    c1 += pr[1][l] * hv;
    c2 += pr[2][l] * hv;
    c3 += pr[3][l] * hv;
  }
  float* cb = ctx_part + ((size_t)b * 16 + chunk) * NH_ * D_ + t;
  cb[0 * D_] = c0;
  cb[1 * D_] = c1;
  cb[2 * D_] = c2;
  cb[3 * D_] = c3;
}

// ---------------------------------------------------------------------------
// outv[b, h*64+u] = ctx[b,h,:] . Wv[h*64+u, :]. Grid (B,NH), 768 thr.
// Reduces the 16 ctx partials on load; wave-per-u dot.
// ---------------------------------------------------------------------------
__global__ __launch_bounds__(768) void outv_kernel(
    const float* __restrict__ ctx_part, const float* __restrict__ Wv,
    float* __restrict__ outv) {
  __shared__ float ch[D_];
  const int b = blockIdx.x, h = blockIdx.y, t = threadIdx.x;
  const int wave = t >> 6, lane = t & 63;
  {
    float a = 0.f;
    #pragma unroll
    for (int c = 0; c < 16; ++c)
      a += ctx_part[(((size_t)b * 16 + c) * NH_ + h) * D_ + t];
    ch[t] = a;
  }
  __syncthreads();
  for (int u = wave; u < HD_; u += 12) {
    const float* wr = Wv + (size_t)(h * HD_ + u) * D_;
    float acc = 0.f;
    #pragma unroll
    for (int k = 0; k < 12; ++k) {
      const int d = lane + (k << 6);
      acc += wr[d] * ch[d];
    }
    #pragma unroll
    for (int o = 32; o > 0; o >>= 1) acc += __shfl_down(acc, o, 64);
    if (lane == 0) outv[b * U_ + h * HD_ + u] = acc;
  }
}

// ---------------------------------------------------------------------------
// new_token[b,d] = bo[d] + outv[b,:] . Wo[d,:]. Grid (B,4), 192 thr (3 waves);
// wave-per-d, lane covers 4 u's via float4.
// ---------------------------------------------------------------------------
__global__ __launch_bounds__(192) void newtoken_kernel(
    const float* __restrict__ outv, const float* __restrict__ Wo,
    const float* __restrict__ bo, float* __restrict__ out0) {
  __shared__ float4 ov4[64];
  const int b = blockIdx.x, q = blockIdx.y, t = threadIdx.x;
  const int wave = t >> 6, lane = t & 63;
  if (t < 64) ov4[t] = ((const float4*)(outv + b * U_))[t];
  __syncthreads();
  const int dbase = q * 192 + wave * 64;
  const float4 o = ov4[lane];
  for (int i = 0; i < 64; ++i) {
    const int d = dbase + i;
    const float4 w = ((const float4*)(Wo + (size_t)d * U_))[lane];
    float acc = w.x * o.x + w.y * o.y + w.z * o.z + w.w * o.w;
    #pragma unroll
    for (int off = 32; off > 0; off >>= 1) acc += __shfl_down(acc, off, 64);
    if (lane == 0)
      out0[((size_t)b * OUTROWS_ + (OUTROWS_ - 1)) * D_ + d] = bo[d] + acc;
  }
}

extern "C" void kernel_launch(void* const* d_in, const int* in_sizes, int n_in,
                              void* d_out, int out_size, void* d_ws, size_t ws_size,
                              hipStream_t stream) {
  const float* hidden = (const float*)d_in[0];
  const float* mask   = (const float*)d_in[1];
  const float* sas    = (const float*)d_in[2];
  const float* Wq     = (const float*)d_in[3];
  const float* Wk     = (const float*)d_in[4];
  const float* Wv     = (const float*)d_in[5];
  const float* Wo     = (const float*)d_in[6];
  const float* bo     = (const float*)d_in[7];

  float* out0 = (float*)d_out;                       // (B,130,D)
  float* out1 = out0 + (size_t)B_ * OUTROWS_ * D_;   // (B,1,1,130)

  // Workspace (floats) — every buffer fully overwritten before read, no init.
  float* part      = (float*)d_ws;                          // B*96*L
  float* sent_part = part + (size_t)B_ * IMP_G_ * L_;       // B*16*D
  float* ctx_part  = sent_part + (size_t)B_ * 16 * D_;      // B*16*NH*D
  float* wqe       = ctx_part + (size_t)B_ * 16 * NH_ * D_; // B*NH*D
  float* scores    = wqe + (size_t)B_ * NH_ * D_;           // B*NH*L
  float* outv      = scores + (size_t)B_ * NH_ * L_;        // B*U

  importance_kernel<<<dim3(48, B_), 256, 0, stream>>>(sas, part);
  sent_kernel<<<dim3(B_, 16), 768, 0, stream>>>(hidden, mask, sent_part);
  qproj_topk_kernel<<<80, 768, 0, stream>>>(sent_part, Wq, Wk, wqe,
                                            part, mask, hidden, out0, out1);
  score_kernel<<<dim3(B_, 16), 256, 0, stream>>>(hidden, mask, wqe, scores);
  ctx_prob_kernel<<<dim3(B_, 16), 768, 0, stream>>>(hidden, scores, ctx_part);
  outv_kernel<<<dim3(B_, NH_), 768, 0, stream>>>(ctx_part, Wv, outv);
  newtoken_kernel<<<dim3(B_, 4), 192, 0, stream>>>(outv, Wo, bo, out0);
}